// Round 11
// baseline (358.883 us; speedup 1.0000x reference)
//
#include <hip/hip_runtime.h>
#include <hip/hip_bf16.h>

#define IN_DIM 128
#define HC 128   // H*C
#define NH 4     // heads
#define CH 32    // channels per head
#define EDGE_DIM 32
#define EB 4096      // edges per scatter block
#define BSH 8        // 256 dsts per bucket

typedef short s8v __attribute__((ext_vector_type(8)));   // 8 bf16 (4 VGPR)
typedef float f4v __attribute__((ext_vector_type(4)));   // mfma acc

// ---------------------------------------------------------------------------
__device__ __forceinline__ unsigned pack_bf16(float a, float b) {
    unsigned ua = __float_as_uint(a), ub = __float_as_uint(b);
    ua += 0x7fffu + ((ua >> 16) & 1u);
    ub += 0x7fffu + ((ub >> 16) & 1u);
    return (ua >> 16) | (ub & 0xffff0000u);
}
__device__ __forceinline__ unsigned short bf16_1(float a) {
    unsigned ua = __float_as_uint(a);
    ua += 0x7fffu + ((ua >> 16) & 1u);
    return (unsigned short)(ua >> 16);
}

// ---------------------------------------------------------------------------
// K0: v_edge[h][k] = sum_c W_edge[k, h*32+c] * att_edge[h, c]   (4x32 floats)
// ---------------------------------------------------------------------------
__global__ void k_vedge(const float* __restrict__ W_edge,
                        const float* __restrict__ att_edge,
                        float* __restrict__ v_edge) {
    int t = threadIdx.x;           // 128 threads
    int h = t >> 5, k = t & 31;
    float s = 0.f;
    #pragma unroll
    for (int c = 0; c < CH; ++c)
        s += W_edge[k * HC + h * CH + c] * att_edge[h * CH + c];
    v_edge[h * EDGE_DIM + k] = s;
}

// ---------------------------------------------------------------------------
// K0b: Wt[n][k] = bf16(W[k][n])
// ---------------------------------------------------------------------------
__global__ __launch_bounds__(256) void k_prep(
    const float* __restrict__ W, unsigned short* __restrict__ Wt) {
    int id = blockIdx.x * 256 + threadIdx.x;   // 64 blocks
    int n = id >> 7, k = id & 127;
    Wt[n * 128 + k] = bf16_1(W[k * 128 + n]);
}

// ---------------------------------------------------------------------------
// K1: x = point_attr @ W via bf16 MFMA (16x16x32). 64 rows/block, 4 waves.
// ---------------------------------------------------------------------------
__global__ __launch_bounds__(256) void k_gemm_mfma(
    const float* __restrict__ A, const unsigned short* __restrict__ Wt,
    unsigned short* __restrict__ xb16, int N)
{
    __shared__ unsigned Al[64 * 64];   // [row][k2], 16 KB, slot-swizzled

    int t = threadIdx.x;
    int node0 = blockIdx.x * 64;

    const float4* A4 = (const float4*)A;
    #pragma unroll
    for (int it = 0; it < 8; ++it) {
        int id = it * 256 + t;
        int row = id >> 5, c = id & 31;
        float4 v = {0.f, 0.f, 0.f, 0.f};
        if (node0 + row < N) v = A4[(size_t)(node0 + row) * 32 + c];
        unsigned u0 = pack_bf16(v.x, v.y);
        unsigned u1 = pack_bf16(v.z, v.w);
        int k2 = 2 * c;
        int slot = k2 >> 2;
        int idx = ((slot ^ (row & 15)) << 2) | (k2 & 3);
        Al[row * 64 + idx]     = u0;
        Al[row * 64 + idx + 1] = u1;
    }
    __syncthreads();

    int l = t & 63;
    int w = t >> 6;
    int lrow = l & 15;
    int lk   = l >> 4;

    s8v afr[4];
    #pragma unroll
    for (int kb = 0; kb < 4; ++kb) {
        int slot = kb * 4 + lk;
        const unsigned* p = &Al[(w * 16 + lrow) * 64 + ((slot ^ lrow) << 2)];
        afr[kb] = *(const s8v*)p;
    }

    #pragma unroll
    for (int ct = 0; ct < 8; ++ct) {
        int col = ct * 16 + lrow;
        f4v acc = {0.f, 0.f, 0.f, 0.f};
        #pragma unroll
        for (int kb = 0; kb < 4; ++kb) {
            s8v bfr = *(const s8v*)&Wt[col * 128 + kb * 32 + lk * 8];
            acc = __builtin_amdgcn_mfma_f32_16x16x32_bf16(afr[kb], bfr, acc, 0, 0, 0);
        }
        #pragma unroll
        for (int r = 0; r < 4; ++r) {
            int node = node0 + w * 16 + lk * 4 + r;
            if (node < N) xb16[(size_t)node * 128 + col] = bf16_1(acc[r]);
        }
    }
}

// ---------------------------------------------------------------------------
// K1b: a_src/a_dst from bf16 x. 16 lanes/node.
// ---------------------------------------------------------------------------
__global__ __launch_bounds__(256) void k_att(
    const unsigned* __restrict__ xb, const float* __restrict__ att_src,
    const float* __restrict__ att_dst, float* __restrict__ a_src,
    float* __restrict__ a_dst, int N)
{
    int t = threadIdx.x;
    int node = blockIdx.x * 16 + (t >> 4);
    int lane = t & 15;
    if (node >= N) return;
    const uint4* x4 = (const uint4*)xb;
    uint4 xv = x4[(size_t)node * 16 + lane];
    int c = lane * 8;
    float xs[8];
    xs[0] = __uint_as_float(xv.x << 16); xs[1] = __uint_as_float(xv.x & 0xffff0000u);
    xs[2] = __uint_as_float(xv.y << 16); xs[3] = __uint_as_float(xv.y & 0xffff0000u);
    xs[4] = __uint_as_float(xv.z << 16); xs[5] = __uint_as_float(xv.z & 0xffff0000u);
    xs[6] = __uint_as_float(xv.w << 16); xs[7] = __uint_as_float(xv.w & 0xffff0000u);
    float ps = 0.f, pd = 0.f;
    #pragma unroll
    for (int i = 0; i < 8; ++i) {
        ps += xs[i] * att_src[c + i];
        pd += xs[i] * att_dst[c + i];
    }
    ps += __shfl_xor(ps, 1); ps += __shfl_xor(ps, 2);
    pd += __shfl_xor(pd, 1); pd += __shfl_xor(pd, 2);
    if ((lane & 3) == 0) {
        a_src[node * 4 + (lane >> 2)] = ps;
        a_dst[node * 4 + (lane >> 2)] = pd;
    }
}

// ---------------------------------------------------------------------------
// K2: degree histogram
// ---------------------------------------------------------------------------
__global__ __launch_bounds__(256) void k_degree(const int* __restrict__ ei,
                                                int* __restrict__ degree, int E) {
    int e = blockIdx.x * 256 + threadIdx.x;
    if (e < E) atomicAdd(&degree[ei[E + e]], 1);
}

// ---------------------------------------------------------------------------
// K3a/b/c: hierarchical exclusive scan (generic, used for degree AND counts)
// ---------------------------------------------------------------------------
__global__ __launch_bounds__(1024) void k_scan_blk(
    const int* __restrict__ degree, int* __restrict__ local,
    int* __restrict__ blocksum, int N)
{
    __shared__ int sums[1024];
    int t = threadIdx.x;
    int base = blockIdx.x * 4096 + t * 4;
    int4 d = {0, 0, 0, 0};
    if (base + 3 < N) d = *(const int4*)&degree[base];
    else {
        if (base + 0 < N) d.x = degree[base + 0];
        if (base + 1 < N) d.y = degree[base + 1];
        if (base + 2 < N) d.z = degree[base + 2];
        if (base + 3 < N) d.w = degree[base + 3];
    }
    int s = d.x + d.y + d.z + d.w;
    sums[t] = s;
    __syncthreads();
    #pragma unroll
    for (int dd = 1; dd < 1024; dd <<= 1) {
        int v = (t >= dd) ? sums[t - dd] : 0;
        __syncthreads();
        sums[t] += v;
        __syncthreads();
    }
    int ex = sums[t] - s;
    if (t == 1023) blocksum[blockIdx.x] = sums[1023];
    int4 o;
    o.x = ex;
    o.y = o.x + d.x;
    o.z = o.y + d.y;
    o.w = o.z + d.z;
    if (base + 3 < N) *(int4*)&local[base] = o;
    else {
        if (base + 0 < N) local[base + 0] = o.x;
        if (base + 1 < N) local[base + 1] = o.y;
        if (base + 2 < N) local[base + 2] = o.z;
        if (base + 3 < N) local[base + 3] = o.w;
    }
}

__global__ __launch_bounds__(1024) void k_scan_top(
    int* __restrict__ blocksum, int nb, int* __restrict__ offsets, int N)
{
    __shared__ int sums[1024];
    int t = threadIdx.x;
    int v = (t < nb) ? blocksum[t] : 0;
    sums[t] = v;
    __syncthreads();
    #pragma unroll
    for (int d = 1; d < 1024; d <<= 1) {
        int u = (t >= d) ? sums[t - d] : 0;
        __syncthreads();
        sums[t] += u;
        __syncthreads();
    }
    if (t < nb) blocksum[t] = sums[t] - v;
    if (t == nb - 1) offsets[N] = sums[t];
}

__global__ __launch_bounds__(1024) void k_scan_add(
    const int* __restrict__ local, const int* __restrict__ blocksum,
    int* __restrict__ offsets, int N)
{
    int base = blockIdx.x * 4096 + threadIdx.x * 4;
    int bs = blocksum[blockIdx.x];
    if (base + 3 < N) {
        int4 o = *(const int4*)&local[base];
        o.x += bs; o.y += bs; o.z += bs; o.w += bs;
        *(int4*)&offsets[base] = o;
    } else {
        for (int j = 0; j < 4; ++j)
            if (base + j < N)
                offsets[base + j] = local[base + j] + bs;
    }
}

// ---------------------------------------------------------------------------
// K4a: per-block bucket histogram over edges -> counts[bin*nblk + blk]
// ---------------------------------------------------------------------------
__global__ __launch_bounds__(256) void k_count1(
    const int* __restrict__ ei, int* __restrict__ counts,
    int E, int nblk, int NBUK)
{
    __shared__ int hist[1024];       // NBUK <= 1024
    int t = threadIdx.x, blk = blockIdx.x;
    for (int i = t; i < NBUK; i += 256) hist[i] = 0;
    __syncthreads();
    int base = blk * EB;
    #pragma unroll
    for (int i = 0; i < EB / 256; ++i) {
        int e = base + i * 256 + t;
        if (e < E) atomicAdd(&hist[ei[E + e] >> BSH], 1);
    }
    __syncthreads();
    for (int i = t; i < NBUK; i += 256)
        counts[(size_t)i * nblk + blk] = hist[i];
}

// ---------------------------------------------------------------------------
// K4b: edge stream -> bucket-grouped records. LDS cursors (no global atomics).
// Each block writes ~10-record contiguous runs per bucket -> L2-mergeable.
// Record: {src, bf16(ae0,ae1), bf16(ae2,ae3), dst}.
// ---------------------------------------------------------------------------
__global__ __launch_bounds__(256) void k_scatter(
    const float* __restrict__ edge_attr, const int* __restrict__ ei,
    const float* __restrict__ v_edge, const int* __restrict__ cscan,
    int4* __restrict__ csr_tmp, int E, int nblk, int NBUK)
{
    __shared__ float vl[HC];
    __shared__ int cur[1024];
    int t = threadIdx.x, blk = blockIdx.x;
    if (t < HC) vl[t] = v_edge[t];
    for (int i = t; i < NBUK; i += 256)
        cur[i] = cscan[(size_t)i * nblk + blk];
    __syncthreads();

    int base = blk * EB;
    #pragma unroll
    for (int i = 0; i < EB / 256; ++i) {
        int e = base + i * 256 + t;
        if (e >= E) continue;
        const float4* ea4 = (const float4*)edge_attr + (size_t)e * 8;
        float ae[4] = {0.f, 0.f, 0.f, 0.f};
        #pragma unroll
        for (int j = 0; j < 8; ++j) {
            float4 v = ea4[j];
            #pragma unroll
            for (int h = 0; h < 4; ++h) {
                const float* vh = &vl[h * 32 + j * 4];
                ae[h] += v.x * vh[0] + v.y * vh[1] + v.z * vh[2] + v.w * vh[3];
            }
        }
        int src = ei[e], dst = ei[E + e];
        int pos = atomicAdd(&cur[dst >> BSH], 1);
        int4 pk;
        pk.x = src;
        pk.y = (int)pack_bf16(ae[0], ae[1]);
        pk.z = (int)pack_bf16(ae[2], ae[3]);
        pk.w = dst;
        csr_tmp[pos] = pk;
    }
}

// ---------------------------------------------------------------------------
// K4c: per-bucket exact-dst placement. Bucket region (~65KB) is L2-hot;
// 256 LDS cursors initialized straight from global offsets.
// ---------------------------------------------------------------------------
__global__ __launch_bounds__(256) void k_bsort(
    const int4* __restrict__ csr_tmp, const int* __restrict__ offsets,
    int4* __restrict__ csr, int N)
{
    __shared__ int cur[256];
    int t = threadIdx.x, b = blockIdx.x;
    int d0 = b << BSH;
    if (d0 + t < N) cur[t] = offsets[d0 + t];
    int hi = d0 + 256; if (hi > N) hi = N;
    int rs = offsets[d0];
    int re = offsets[hi];
    __syncthreads();
    for (int i = rs + t; i < re; i += 256) {
        int4 rec = csr_tmp[i];
        int pos = atomicAdd(&cur[rec.w - d0], 1);
        csr[pos] = rec;
    }
}

// ---------------------------------------------------------------------------
// K5: fused pull, 16 lanes/node. logit finish + softmax + weighted sum +
// bias + LN + LeakyReLU. 4-edge groups with 1-ahead prefetch.
// ---------------------------------------------------------------------------
__global__ __launch_bounds__(256) void k_agg(
    const int* __restrict__ offsets, const int4* __restrict__ csr,
    const float* __restrict__ a_src, const float* __restrict__ a_dst,
    const unsigned* __restrict__ xb, const float* __restrict__ bias,
    const float* __restrict__ gamma, const float* __restrict__ beta,
    float* __restrict__ out, int N)
{
    int t = threadIdx.x;
    int node = blockIdx.x * 16 + (t >> 4);
    int lane = t & 15;
    if (node >= N) return;
    int st = offsets[node], en = offsets[node + 1];
    int hsel = lane >> 2;
    float adst = a_dst[node * 4 + hsel];
    const uint4* x4 = (const uint4*)xb;
    float acc[8] = {0.f, 0.f, 0.f, 0.f, 0.f, 0.f, 0.f, 0.f};
    float denom = 0.f;

    int s_c[4]; float ae_c[4], as_c[4];

    if (st < en) {
        #pragma unroll
        for (int j = 0; j < 4; ++j) {
            bool v = (st + j) < en;
            int a = v ? (st + j) : st;
            int4 pk = csr[a];
            s_c[j] = pk.x;
            unsigned w = (hsel & 2) ? (unsigned)pk.z : (unsigned)pk.y;
            float e = __uint_as_float((hsel & 1) ? (w & 0xffff0000u) : (w << 16));
            ae_c[j] = v ? e : -1e30f;
        }
        #pragma unroll
        for (int j = 0; j < 4; ++j) as_c[j] = a_src[s_c[j] * 4 + hsel];

        for (int p = st; p < en; p += 4) {
            int pn = p + 4;
            int s_n[4]; float ae_n[4], as_n[4];
            #pragma unroll
            for (int j = 0; j < 4; ++j) {
                bool v = (pn + j) < en;
                int a = v ? (pn + j) : st;
                int4 pk = csr[a];
                s_n[j] = pk.x;
                unsigned w = (hsel & 2) ? (unsigned)pk.z : (unsigned)pk.y;
                float e = __uint_as_float((hsel & 1) ? (w & 0xffff0000u) : (w << 16));
                ae_n[j] = v ? e : -1e30f;
            }
            #pragma unroll
            for (int j = 0; j < 4; ++j) as_n[j] = a_src[s_n[j] * 4 + hsel];

            #pragma unroll
            for (int j = 0; j < 4; ++j) {
                float al = as_c[j] + adst + ae_c[j];
                al = (al < 0.f) ? 0.2f * al : al;
                float ex = __expf(al);
                denom += ex;
                uint4 xv = x4[(size_t)s_c[j] * 16 + lane];
                acc[0] += ex * __uint_as_float(xv.x << 16);
                acc[1] += ex * __uint_as_float(xv.x & 0xffff0000u);
                acc[2] += ex * __uint_as_float(xv.y << 16);
                acc[3] += ex * __uint_as_float(xv.y & 0xffff0000u);
                acc[4] += ex * __uint_as_float(xv.z << 16);
                acc[5] += ex * __uint_as_float(xv.z & 0xffff0000u);
                acc[6] += ex * __uint_as_float(xv.w << 16);
                acc[7] += ex * __uint_as_float(xv.w & 0xffff0000u);
            }
            #pragma unroll
            for (int j = 0; j < 4; ++j) {
                s_c[j] = s_n[j]; ae_c[j] = ae_n[j]; as_c[j] = as_n[j];
            }
        }
    }
    float inv = 1.f / (denom + 1e-16f);
    int c = lane * 8;
    float4 b0 = *(const float4*)&bias[c];
    float4 b1 = *(const float4*)&bias[c + 4];
    float o[8];
    o[0] = acc[0] * inv + b0.x; o[1] = acc[1] * inv + b0.y;
    o[2] = acc[2] * inv + b0.z; o[3] = acc[3] * inv + b0.w;
    o[4] = acc[4] * inv + b1.x; o[5] = acc[5] * inv + b1.y;
    o[6] = acc[6] * inv + b1.z; o[7] = acc[7] * inv + b1.w;

    float s = 0.f;
    #pragma unroll
    for (int i = 0; i < 8; ++i) s += o[i];
    #pragma unroll
    for (int m = 1; m < 16; m <<= 1) s += __shfl_xor(s, m, 16);
    float mu = s * (1.0f / 128.0f);
    float q = 0.f;
    #pragma unroll
    for (int i = 0; i < 8; ++i) { o[i] -= mu; q += o[i] * o[i]; }
    #pragma unroll
    for (int m = 1; m < 16; m <<= 1) q += __shfl_xor(q, m, 16);
    float rstd = rsqrtf(q * (1.0f / 128.0f) + 1e-5f);
    float4 g0 = *(const float4*)&gamma[c];
    float4 g1 = *(const float4*)&gamma[c + 4];
    float4 e0 = *(const float4*)&beta[c];
    float4 e1 = *(const float4*)&beta[c + 4];
    float y[8];
    y[0] = o[0] * rstd * g0.x + e0.x; y[1] = o[1] * rstd * g0.y + e0.y;
    y[2] = o[2] * rstd * g0.z + e0.z; y[3] = o[3] * rstd * g0.w + e0.w;
    y[4] = o[4] * rstd * g1.x + e1.x; y[5] = o[5] * rstd * g1.y + e1.y;
    y[6] = o[6] * rstd * g1.z + e1.z; y[7] = o[7] * rstd * g1.w + e1.w;
    #pragma unroll
    for (int i = 0; i < 8; ++i) y[i] = (y[i] < 0.f) ? 0.01f * y[i] : y[i];
    float4 r0 = {y[0], y[1], y[2], y[3]};
    float4 r1 = {y[4], y[5], y[6], y[7]};
    float4* op = (float4*)out + (size_t)node * 32 + lane * 2;
    op[0] = r0;
    op[1] = r1;
}

// ---------------------------------------------------------------------------
extern "C" void kernel_launch(void* const* d_in, const int* in_sizes, int n_in,
                              void* d_out, int out_size, void* d_ws, size_t ws_size,
                              hipStream_t stream) {
    const float* point_attr = (const float*)d_in[0];
    const int*   edge_index = (const int*)d_in[1];
    const float* edge_attr  = (const float*)d_in[2];
    const float* W          = (const float*)d_in[3];
    const float* att_src    = (const float*)d_in[4];
    const float* att_dst    = (const float*)d_in[5];
    const float* W_edge     = (const float*)d_in[6];
    const float* att_edge   = (const float*)d_in[7];
    const float* bias       = (const float*)d_in[8];
    const float* ln_gamma   = (const float*)d_in[9];
    const float* ln_beta    = (const float*)d_in[10];

    int N = in_sizes[0] / IN_DIM;
    int E = in_sizes[2] / EDGE_DIM;
    float* out = (float*)d_out;

    char* ws = (char*)d_ws;
    size_t off = 0;
    auto alloc = [&](size_t bytes) {
        void* p = ws + off;
        off += (bytes + 255) & ~(size_t)255;
        return p;
    };
    unsigned* xb     = (unsigned*)alloc((size_t)N * 128 * 2);   // bf16 x
    float* a_src     = (float*)alloc((size_t)N * 4 * 4);
    float* a_dst     = (float*)alloc((size_t)N * 4 * 4);
    int*   degree    = (int*)alloc((size_t)N * 4);
    int*   offsets   = (int*)alloc((size_t)(N + 1) * 4);
    int*   scanloc   = (int*)alloc((size_t)N * 4);
    int*   blocksum  = (int*)alloc(1024 * 4);
    float* v_edge    = (float*)alloc(128 * 4);
    unsigned short* Wt = (unsigned short*)alloc(128 * 128 * 2);
    int4*  csr       = (int4*)alloc((size_t)E * 16);
    int4*  csr_tmp   = (int4*)alloc((size_t)E * 16);

    int nblk = (E + EB - 1) / EB;                 // scatter blocks
    int NBUK = (N + (1 << BSH) - 1) >> BSH;       // dst buckets (<=1024)
    int L = NBUK * nblk;                          // counts length
    int*   counts    = (int*)alloc((size_t)L * 4);
    int*   cl2       = (int*)alloc((size_t)L * 4);
    int*   cscan     = (int*)alloc((size_t)(L + 1) * 4);
    int*   bs2       = (int*)alloc(1024 * 4);

    hipMemsetAsync(degree, 0, (size_t)N * 4, stream);

    int nb  = (N + 4095) / 4096;
    int nb2 = (L + 4095) / 4096;

    k_vedge<<<1, 128, 0, stream>>>(W_edge, att_edge, v_edge);
    k_prep<<<64, 256, 0, stream>>>(W, Wt);
    k_gemm_mfma<<<(N + 63) / 64, 256, 0, stream>>>(point_attr, Wt,
                                                   (unsigned short*)xb, N);
    k_att<<<(N + 15) / 16, 256, 0, stream>>>(xb, att_src, att_dst,
                                             a_src, a_dst, N);
    // degree -> offsets
    k_degree<<<(E + 255) / 256, 256, 0, stream>>>(edge_index, degree, E);
    k_scan_blk<<<nb, 1024, 0, stream>>>(degree, scanloc, blocksum, N);
    k_scan_top<<<1, 1024, 0, stream>>>(blocksum, nb, offsets, N);
    k_scan_add<<<nb, 1024, 0, stream>>>(scanloc, blocksum, offsets, N);
    // bucket counts -> per-(bin,blk) bases
    k_count1<<<nblk, 256, 0, stream>>>(edge_index, counts, E, nblk, NBUK);
    k_scan_blk<<<nb2, 1024, 0, stream>>>(counts, cl2, bs2, L);
    k_scan_top<<<1, 1024, 0, stream>>>(bs2, nb2, cscan, L);
    k_scan_add<<<nb2, 1024, 0, stream>>>(cl2, bs2, cscan, L);
    // grouped scatter + in-bucket exact placement
    k_scatter<<<nblk, 256, 0, stream>>>(edge_attr, edge_index, v_edge,
                                        cscan, csr_tmp, E, nblk, NBUK);
    k_bsort<<<NBUK, 256, 0, stream>>>(csr_tmp, offsets, csr, N);
    k_agg<<<(N + 15) / 16, 256, 0, stream>>>(offsets, csr, a_src, a_dst, xb,
                                             bias, ln_gamma, ln_beta, out, N);
}

// Round 12
// 353.835 us; speedup vs baseline: 1.0143x; 1.0143x over previous
//
#include <hip/hip_runtime.h>
#include <hip/hip_bf16.h>

#define IN_DIM 128
#define HC 128   // H*C
#define NH 4     // heads
#define CH 32    // channels per head
#define EDGE_DIM 32
#define EB 4096      // edges per scatter block
#define BSH 8        // 256 dsts per bucket

typedef short s8v __attribute__((ext_vector_type(8)));   // 8 bf16 (4 VGPR)
typedef float f4v __attribute__((ext_vector_type(4)));   // mfma acc

// ---------------------------------------------------------------------------
__device__ __forceinline__ unsigned pack_bf16(float a, float b) {
    unsigned ua = __float_as_uint(a), ub = __float_as_uint(b);
    ua += 0x7fffu + ((ua >> 16) & 1u);
    ub += 0x7fffu + ((ub >> 16) & 1u);
    return (ua >> 16) | (ub & 0xffff0000u);
}
__device__ __forceinline__ unsigned short bf16_1(float a) {
    unsigned ua = __float_as_uint(a);
    ua += 0x7fffu + ((ua >> 16) & 1u);
    return (unsigned short)(ua >> 16);
}

// ---------------------------------------------------------------------------
// K0: v_edge[h][k] = sum_c W_edge[k, h*32+c] * att_edge[h, c]   (4x32 floats)
// ---------------------------------------------------------------------------
__global__ void k_vedge(const float* __restrict__ W_edge,
                        const float* __restrict__ att_edge,
                        float* __restrict__ v_edge) {
    int t = threadIdx.x;           // 128 threads
    int h = t >> 5, k = t & 31;
    float s = 0.f;
    #pragma unroll
    for (int c = 0; c < CH; ++c)
        s += W_edge[k * HC + h * CH + c] * att_edge[h * CH + c];
    v_edge[h * EDGE_DIM + k] = s;
}

// ---------------------------------------------------------------------------
// K0b: Wt[n][k] = bf16(W[k][n])
// ---------------------------------------------------------------------------
__global__ __launch_bounds__(256) void k_prep(
    const float* __restrict__ W, unsigned short* __restrict__ Wt) {
    int id = blockIdx.x * 256 + threadIdx.x;   // 64 blocks
    int n = id >> 7, k = id & 127;
    Wt[n * 128 + k] = bf16_1(W[k * 128 + n]);
}

// ---------------------------------------------------------------------------
// K1: x = point_attr @ W via bf16 MFMA (16x16x32). 64 rows/block, 4 waves.
// ---------------------------------------------------------------------------
__global__ __launch_bounds__(256) void k_gemm_mfma(
    const float* __restrict__ A, const unsigned short* __restrict__ Wt,
    unsigned short* __restrict__ xb16, int N)
{
    __shared__ unsigned Al[64 * 64];   // [row][k2], 16 KB, slot-swizzled

    int t = threadIdx.x;
    int node0 = blockIdx.x * 64;

    const float4* A4 = (const float4*)A;
    #pragma unroll
    for (int it = 0; it < 8; ++it) {
        int id = it * 256 + t;
        int row = id >> 5, c = id & 31;
        float4 v = {0.f, 0.f, 0.f, 0.f};
        if (node0 + row < N) v = A4[(size_t)(node0 + row) * 32 + c];
        unsigned u0 = pack_bf16(v.x, v.y);
        unsigned u1 = pack_bf16(v.z, v.w);
        int k2 = 2 * c;
        int slot = k2 >> 2;
        int idx = ((slot ^ (row & 15)) << 2) | (k2 & 3);
        Al[row * 64 + idx]     = u0;
        Al[row * 64 + idx + 1] = u1;
    }
    __syncthreads();

    int l = t & 63;
    int w = t >> 6;
    int lrow = l & 15;
    int lk   = l >> 4;

    s8v afr[4];
    #pragma unroll
    for (int kb = 0; kb < 4; ++kb) {
        int slot = kb * 4 + lk;
        const unsigned* p = &Al[(w * 16 + lrow) * 64 + ((slot ^ lrow) << 2)];
        afr[kb] = *(const s8v*)p;
    }

    #pragma unroll
    for (int ct = 0; ct < 8; ++ct) {
        int col = ct * 16 + lrow;
        f4v acc = {0.f, 0.f, 0.f, 0.f};
        #pragma unroll
        for (int kb = 0; kb < 4; ++kb) {
            s8v bfr = *(const s8v*)&Wt[col * 128 + kb * 32 + lk * 8];
            acc = __builtin_amdgcn_mfma_f32_16x16x32_bf16(afr[kb], bfr, acc, 0, 0, 0);
        }
        #pragma unroll
        for (int r = 0; r < 4; ++r) {
            int node = node0 + w * 16 + lk * 4 + r;
            if (node < N) xb16[(size_t)node * 128 + col] = bf16_1(acc[r]);
        }
    }
}

// ---------------------------------------------------------------------------
// K1b: a_src/a_dst from bf16 x. 16 lanes/node.
// ---------------------------------------------------------------------------
__global__ __launch_bounds__(256) void k_att(
    const unsigned* __restrict__ xb, const float* __restrict__ att_src,
    const float* __restrict__ att_dst, float* __restrict__ a_src,
    float* __restrict__ a_dst, int N)
{
    int t = threadIdx.x;
    int node = blockIdx.x * 16 + (t >> 4);
    int lane = t & 15;
    if (node >= N) return;
    const uint4* x4 = (const uint4*)xb;
    uint4 xv = x4[(size_t)node * 16 + lane];
    int c = lane * 8;
    float xs[8];
    xs[0] = __uint_as_float(xv.x << 16); xs[1] = __uint_as_float(xv.x & 0xffff0000u);
    xs[2] = __uint_as_float(xv.y << 16); xs[3] = __uint_as_float(xv.y & 0xffff0000u);
    xs[4] = __uint_as_float(xv.z << 16); xs[5] = __uint_as_float(xv.z & 0xffff0000u);
    xs[6] = __uint_as_float(xv.w << 16); xs[7] = __uint_as_float(xv.w & 0xffff0000u);
    float ps = 0.f, pd = 0.f;
    #pragma unroll
    for (int i = 0; i < 8; ++i) {
        ps += xs[i] * att_src[c + i];
        pd += xs[i] * att_dst[c + i];
    }
    ps += __shfl_xor(ps, 1); ps += __shfl_xor(ps, 2);
    pd += __shfl_xor(pd, 1); pd += __shfl_xor(pd, 2);
    if ((lane & 3) == 0) {
        a_src[node * 4 + (lane >> 2)] = ps;
        a_dst[node * 4 + (lane >> 2)] = pd;
    }
}

// ---------------------------------------------------------------------------
// K2: degree histogram
// ---------------------------------------------------------------------------
__global__ __launch_bounds__(256) void k_degree(const int* __restrict__ ei,
                                                int* __restrict__ degree, int E) {
    int e = blockIdx.x * 256 + threadIdx.x;
    if (e < E) atomicAdd(&degree[ei[E + e]], 1);
}

// ---------------------------------------------------------------------------
// K3a/b/c: hierarchical exclusive scan (generic)
// ---------------------------------------------------------------------------
__global__ __launch_bounds__(1024) void k_scan_blk(
    const int* __restrict__ degree, int* __restrict__ local,
    int* __restrict__ blocksum, int N)
{
    __shared__ int sums[1024];
    int t = threadIdx.x;
    int base = blockIdx.x * 4096 + t * 4;
    int4 d = {0, 0, 0, 0};
    if (base + 3 < N) d = *(const int4*)&degree[base];
    else {
        if (base + 0 < N) d.x = degree[base + 0];
        if (base + 1 < N) d.y = degree[base + 1];
        if (base + 2 < N) d.z = degree[base + 2];
        if (base + 3 < N) d.w = degree[base + 3];
    }
    int s = d.x + d.y + d.z + d.w;
    sums[t] = s;
    __syncthreads();
    #pragma unroll
    for (int dd = 1; dd < 1024; dd <<= 1) {
        int v = (t >= dd) ? sums[t - dd] : 0;
        __syncthreads();
        sums[t] += v;
        __syncthreads();
    }
    int ex = sums[t] - s;
    if (t == 1023) blocksum[blockIdx.x] = sums[1023];
    int4 o;
    o.x = ex;
    o.y = o.x + d.x;
    o.z = o.y + d.y;
    o.w = o.z + d.z;
    if (base + 3 < N) *(int4*)&local[base] = o;
    else {
        if (base + 0 < N) local[base + 0] = o.x;
        if (base + 1 < N) local[base + 1] = o.y;
        if (base + 2 < N) local[base + 2] = o.z;
        if (base + 3 < N) local[base + 3] = o.w;
    }
}

__global__ __launch_bounds__(1024) void k_scan_top(
    int* __restrict__ blocksum, int nb, int* __restrict__ offsets, int N)
{
    __shared__ int sums[1024];
    int t = threadIdx.x;
    int v = (t < nb) ? blocksum[t] : 0;
    sums[t] = v;
    __syncthreads();
    #pragma unroll
    for (int d = 1; d < 1024; d <<= 1) {
        int u = (t >= d) ? sums[t - d] : 0;
        __syncthreads();
        sums[t] += u;
        __syncthreads();
    }
    if (t < nb) blocksum[t] = sums[t] - v;
    if (t == nb - 1) offsets[N] = sums[t];
}

__global__ __launch_bounds__(1024) void k_scan_add(
    const int* __restrict__ local, const int* __restrict__ blocksum,
    int* __restrict__ offsets, int N)
{
    int base = blockIdx.x * 4096 + threadIdx.x * 4;
    int bs = blocksum[blockIdx.x];
    if (base + 3 < N) {
        int4 o = *(const int4*)&local[base];
        o.x += bs; o.y += bs; o.z += bs; o.w += bs;
        *(int4*)&offsets[base] = o;
    } else {
        for (int j = 0; j < 4; ++j)
            if (base + j < N)
                offsets[base + j] = local[base + j] + bs;
    }
}

// ---------------------------------------------------------------------------
// K4a: per-block bucket histogram -> counts[bin*nblk + blk]. 1024 threads.
// ---------------------------------------------------------------------------
__global__ __launch_bounds__(1024) void k_count1(
    const int* __restrict__ ei, int* __restrict__ counts,
    int E, int nblk, int NBUK)
{
    __shared__ int hist[1024];       // NBUK <= 1024
    int t = threadIdx.x, blk = blockIdx.x;
    if (t < NBUK) hist[t] = 0;
    __syncthreads();
    int base = blk * EB;
    #pragma unroll
    for (int i = 0; i < EB / 1024; ++i) {
        int e = base + i * 1024 + t;
        if (e < E) atomicAdd(&hist[ei[E + e] >> BSH], 1);
    }
    __syncthreads();
    if (t < NBUK) counts[(size_t)t * nblk + blk] = hist[t];
}

// ---------------------------------------------------------------------------
// K4b: edge stream -> bucket-grouped records, LDS cursors. 1024 threads,
// 4 edges/thread. Contiguous ~10-record runs per (bucket, block).
// ---------------------------------------------------------------------------
__global__ __launch_bounds__(1024) void k_scatter(
    const float* __restrict__ edge_attr, const int* __restrict__ ei,
    const float* __restrict__ v_edge, const int* __restrict__ cscan,
    int4* __restrict__ csr_tmp, int E, int nblk, int NBUK)
{
    __shared__ float vl[HC];
    __shared__ int cur[1024];
    int t = threadIdx.x, blk = blockIdx.x;
    if (t < HC) vl[t] = v_edge[t];
    if (t < NBUK) cur[t] = cscan[(size_t)t * nblk + blk];
    __syncthreads();

    int base = blk * EB;
    #pragma unroll
    for (int i = 0; i < EB / 1024; ++i) {
        int e = base + i * 1024 + t;
        if (e >= E) continue;
        const float4* ea4 = (const float4*)edge_attr + (size_t)e * 8;
        float ae[4] = {0.f, 0.f, 0.f, 0.f};
        #pragma unroll
        for (int j = 0; j < 8; ++j) {
            float4 v = ea4[j];
            #pragma unroll
            for (int h = 0; h < 4; ++h) {
                const float* vh = &vl[h * 32 + j * 4];
                ae[h] += v.x * vh[0] + v.y * vh[1] + v.z * vh[2] + v.w * vh[3];
            }
        }
        int src = ei[e], dst = ei[E + e];
        int pos = atomicAdd(&cur[dst >> BSH], 1);
        int4 pk;
        pk.x = src;
        pk.y = (int)pack_bf16(ae[0], ae[1]);
        pk.z = (int)pack_bf16(ae[2], ae[3]);
        pk.w = dst;
        csr_tmp[pos] = pk;
    }
}

// ---------------------------------------------------------------------------
// K4c: per-bucket exact-dst placement, 1024 threads, L2-hot window.
// ---------------------------------------------------------------------------
__global__ __launch_bounds__(1024) void k_bsort(
    const int4* __restrict__ csr_tmp, const int* __restrict__ offsets,
    int4* __restrict__ csr, int N)
{
    __shared__ int cur[256];
    int t = threadIdx.x, b = blockIdx.x;
    int d0 = b << BSH;
    if (t < 256 && d0 + t < N) cur[t] = offsets[d0 + t];
    int hi = d0 + 256; if (hi > N) hi = N;
    int rs = offsets[d0];
    int re = offsets[hi];
    __syncthreads();
    for (int i = rs + t; i < re; i += 1024) {
        int4 rec = csr_tmp[i];
        int pos = atomicAdd(&cur[rec.w - d0], 1);
        csr[pos] = rec;
    }
}

// ---------------------------------------------------------------------------
// K5: fused pull, 16 lanes/node. logit finish + softmax + weighted sum +
// bias + LN + LeakyReLU. 4-edge groups with 1-ahead prefetch.
// ---------------------------------------------------------------------------
__global__ __launch_bounds__(256) void k_agg(
    const int* __restrict__ offsets, const int4* __restrict__ csr,
    const float* __restrict__ a_src, const float* __restrict__ a_dst,
    const unsigned* __restrict__ xb, const float* __restrict__ bias,
    const float* __restrict__ gamma, const float* __restrict__ beta,
    float* __restrict__ out, int N)
{
    int t = threadIdx.x;
    int node = blockIdx.x * 16 + (t >> 4);
    int lane = t & 15;
    if (node >= N) return;
    int st = offsets[node], en = offsets[node + 1];
    int hsel = lane >> 2;
    float adst = a_dst[node * 4 + hsel];
    const uint4* x4 = (const uint4*)xb;
    float acc[8] = {0.f, 0.f, 0.f, 0.f, 0.f, 0.f, 0.f, 0.f};
    float denom = 0.f;

    int s_c[4]; float ae_c[4], as_c[4];

    if (st < en) {
        #pragma unroll
        for (int j = 0; j < 4; ++j) {
            bool v = (st + j) < en;
            int a = v ? (st + j) : st;
            int4 pk = csr[a];
            s_c[j] = pk.x;
            unsigned w = (hsel & 2) ? (unsigned)pk.z : (unsigned)pk.y;
            float e = __uint_as_float((hsel & 1) ? (w & 0xffff0000u) : (w << 16));
            ae_c[j] = v ? e : -1e30f;
        }
        #pragma unroll
        for (int j = 0; j < 4; ++j) as_c[j] = a_src[s_c[j] * 4 + hsel];

        for (int p = st; p < en; p += 4) {
            int pn = p + 4;
            int s_n[4]; float ae_n[4], as_n[4];
            #pragma unroll
            for (int j = 0; j < 4; ++j) {
                bool v = (pn + j) < en;
                int a = v ? (pn + j) : st;
                int4 pk = csr[a];
                s_n[j] = pk.x;
                unsigned w = (hsel & 2) ? (unsigned)pk.z : (unsigned)pk.y;
                float e = __uint_as_float((hsel & 1) ? (w & 0xffff0000u) : (w << 16));
                ae_n[j] = v ? e : -1e30f;
            }
            #pragma unroll
            for (int j = 0; j < 4; ++j) as_n[j] = a_src[s_n[j] * 4 + hsel];

            #pragma unroll
            for (int j = 0; j < 4; ++j) {
                float al = as_c[j] + adst + ae_c[j];
                al = (al < 0.f) ? 0.2f * al : al;
                float ex = __expf(al);
                denom += ex;
                uint4 xv = x4[(size_t)s_c[j] * 16 + lane];
                acc[0] += ex * __uint_as_float(xv.x << 16);
                acc[1] += ex * __uint_as_float(xv.x & 0xffff0000u);
                acc[2] += ex * __uint_as_float(xv.y << 16);
                acc[3] += ex * __uint_as_float(xv.y & 0xffff0000u);
                acc[4] += ex * __uint_as_float(xv.z << 16);
                acc[5] += ex * __uint_as_float(xv.z & 0xffff0000u);
                acc[6] += ex * __uint_as_float(xv.w << 16);
                acc[7] += ex * __uint_as_float(xv.w & 0xffff0000u);
            }
            #pragma unroll
            for (int j = 0; j < 4; ++j) {
                s_c[j] = s_n[j]; ae_c[j] = ae_n[j]; as_c[j] = as_n[j];
            }
        }
    }
    float inv = 1.f / (denom + 1e-16f);
    int c = lane * 8;
    float4 b0 = *(const float4*)&bias[c];
    float4 b1 = *(const float4*)&bias[c + 4];
    float o[8];
    o[0] = acc[0] * inv + b0.x; o[1] = acc[1] * inv + b0.y;
    o[2] = acc[2] * inv + b0.z; o[3] = acc[3] * inv + b0.w;
    o[4] = acc[4] * inv + b1.x; o[5] = acc[5] * inv + b1.y;
    o[6] = acc[6] * inv + b1.z; o[7] = acc[7] * inv + b1.w;

    float s = 0.f;
    #pragma unroll
    for (int i = 0; i < 8; ++i) s += o[i];
    #pragma unroll
    for (int m = 1; m < 16; m <<= 1) s += __shfl_xor(s, m, 16);
    float mu = s * (1.0f / 128.0f);
    float q = 0.f;
    #pragma unroll
    for (int i = 0; i < 8; ++i) { o[i] -= mu; q += o[i] * o[i]; }
    #pragma unroll
    for (int m = 1; m < 16; m <<= 1) q += __shfl_xor(q, m, 16);
    float rstd = rsqrtf(q * (1.0f / 128.0f) + 1e-5f);
    float4 g0 = *(const float4*)&gamma[c];
    float4 g1 = *(const float4*)&gamma[c + 4];
    float4 e0 = *(const float4*)&beta[c];
    float4 e1 = *(const float4*)&beta[c + 4];
    float y[8];
    y[0] = o[0] * rstd * g0.x + e0.x; y[1] = o[1] * rstd * g0.y + e0.y;
    y[2] = o[2] * rstd * g0.z + e0.z; y[3] = o[3] * rstd * g0.w + e0.w;
    y[4] = o[4] * rstd * g1.x + e1.x; y[5] = o[5] * rstd * g1.y + e1.y;
    y[6] = o[6] * rstd * g1.z + e1.z; y[7] = o[7] * rstd * g1.w + e1.w;
    #pragma unroll
    for (int i = 0; i < 8; ++i) y[i] = (y[i] < 0.f) ? 0.01f * y[i] : y[i];
    float4 r0 = {y[0], y[1], y[2], y[3]};
    float4 r1 = {y[4], y[5], y[6], y[7]};
    float4* op = (float4*)out + (size_t)node * 32 + lane * 2;
    op[0] = r0;
    op[1] = r1;
}

// ---------------------------------------------------------------------------
extern "C" void kernel_launch(void* const* d_in, const int* in_sizes, int n_in,
                              void* d_out, int out_size, void* d_ws, size_t ws_size,
                              hipStream_t stream) {
    const float* point_attr = (const float*)d_in[0];
    const int*   edge_index = (const int*)d_in[1];
    const float* edge_attr  = (const float*)d_in[2];
    const float* W          = (const float*)d_in[3];
    const float* att_src    = (const float*)d_in[4];
    const float* att_dst    = (const float*)d_in[5];
    const float* W_edge     = (const float*)d_in[6];
    const float* att_edge   = (const float*)d_in[7];
    const float* bias       = (const float*)d_in[8];
    const float* ln_gamma   = (const float*)d_in[9];
    const float* ln_beta    = (const float*)d_in[10];

    int N = in_sizes[0] / IN_DIM;
    int E = in_sizes[2] / EDGE_DIM;
    float* out = (float*)d_out;

    char* ws = (char*)d_ws;
    size_t off = 0;
    auto alloc = [&](size_t bytes) {
        void* p = ws + off;
        off += (bytes + 255) & ~(size_t)255;
        return p;
    };
    unsigned* xb     = (unsigned*)alloc((size_t)N * 128 * 2);   // bf16 x
    float* a_src     = (float*)alloc((size_t)N * 4 * 4);
    float* a_dst     = (float*)alloc((size_t)N * 4 * 4);
    int*   degree    = (int*)alloc((size_t)N * 4);
    int*   offsets   = (int*)alloc((size_t)(N + 1) * 4);
    int*   scanloc   = (int*)alloc((size_t)N * 4);
    int*   blocksum  = (int*)alloc(1024 * 4);
    float* v_edge    = (float*)alloc(128 * 4);
    unsigned short* Wt = (unsigned short*)alloc(128 * 128 * 2);
    int4*  csr       = (int4*)alloc((size_t)E * 16);
    int4*  csr_tmp   = (int4*)alloc((size_t)E * 16);

    int nblk = (E + EB - 1) / EB;                 // scatter blocks
    int NBUK = (N + (1 << BSH) - 1) >> BSH;       // dst buckets (<=1024)
    int L = NBUK * nblk;                          // counts length
    int*   counts    = (int*)alloc((size_t)L * 4);
    int*   cl2       = (int*)alloc((size_t)L * 4);
    int*   cscan     = (int*)alloc((size_t)(L + 1) * 4);
    int*   bs2       = (int*)alloc(1024 * 4);

    hipMemsetAsync(degree, 0, (size_t)N * 4, stream);

    int nb  = (N + 4095) / 4096;
    int nb2 = (L + 4095) / 4096;

    k_vedge<<<1, 128, 0, stream>>>(W_edge, att_edge, v_edge);
    k_prep<<<64, 256, 0, stream>>>(W, Wt);
    k_gemm_mfma<<<(N + 63) / 64, 256, 0, stream>>>(point_attr, Wt,
                                                   (unsigned short*)xb, N);
    k_att<<<(N + 15) / 16, 256, 0, stream>>>(xb, att_src, att_dst,
                                             a_src, a_dst, N);
    // degree -> offsets
    k_degree<<<(E + 255) / 256, 256, 0, stream>>>(edge_index, degree, E);
    k_scan_blk<<<nb, 1024, 0, stream>>>(degree, scanloc, blocksum, N);
    k_scan_top<<<1, 1024, 0, stream>>>(blocksum, nb, offsets, N);
    k_scan_add<<<nb, 1024, 0, stream>>>(scanloc, blocksum, offsets, N);
    // bucket counts -> per-(bin,blk) bases
    k_count1<<<nblk, 1024, 0, stream>>>(edge_index, counts, E, nblk, NBUK);
    k_scan_blk<<<nb2, 1024, 0, stream>>>(counts, cl2, bs2, L);
    k_scan_top<<<1, 1024, 0, stream>>>(bs2, nb2, cscan, L);
    k_scan_add<<<nb2, 1024, 0, stream>>>(cl2, bs2, cscan, L);
    // grouped scatter + in-bucket exact placement
    k_scatter<<<nblk, 1024, 0, stream>>>(edge_attr, edge_index, v_edge,
                                         cscan, csr_tmp, E, nblk, NBUK);
    k_bsort<<<NBUK, 1024, 0, stream>>>(csr_tmp, offsets, csr, N);
    k_agg<<<(N + 15) / 16, 256, 0, stream>>>(offsets, csr, a_src, a_dst, xb,
                                             bias, ln_gamma, ln_beta, out, N);
}

// Round 13
// 324.976 us; speedup vs baseline: 1.1043x; 1.0888x over previous
//
#include <hip/hip_runtime.h>
#include <hip/hip_bf16.h>

#define IN_DIM 128
#define HC 128   // H*C
#define NH 4     // heads
#define CH 32    // channels per head
#define EDGE_DIM 32

typedef short s8v __attribute__((ext_vector_type(8)));   // 8 bf16 (4 VGPR)
typedef float f4v __attribute__((ext_vector_type(4)));   // mfma acc

// ---------------------------------------------------------------------------
__device__ __forceinline__ unsigned pack_bf16(float a, float b) {
    unsigned ua = __float_as_uint(a), ub = __float_as_uint(b);
    ua += 0x7fffu + ((ua >> 16) & 1u);
    ub += 0x7fffu + ((ub >> 16) & 1u);
    return (ua >> 16) | (ub & 0xffff0000u);
}
__device__ __forceinline__ unsigned short bf16_1(float a) {
    unsigned ua = __float_as_uint(a);
    ua += 0x7fffu + ((ua >> 16) & 1u);
    return (unsigned short)(ua >> 16);
}

// ---------------------------------------------------------------------------
// K0: v_edge[h][k] = sum_c W_edge[k, h*32+c] * att_edge[h, c]   (4x32 floats)
// ---------------------------------------------------------------------------
__global__ void k_vedge(const float* __restrict__ W_edge,
                        const float* __restrict__ att_edge,
                        float* __restrict__ v_edge) {
    int t = threadIdx.x;           // 128 threads
    int h = t >> 5, k = t & 31;
    float s = 0.f;
    #pragma unroll
    for (int c = 0; c < CH; ++c)
        s += W_edge[k * HC + h * CH + c] * att_edge[h * CH + c];
    v_edge[h * EDGE_DIM + k] = s;
}

// ---------------------------------------------------------------------------
// K0b: Wt[n][k] = bf16(W[k][n])
// ---------------------------------------------------------------------------
__global__ __launch_bounds__(256) void k_prep(
    const float* __restrict__ W, unsigned short* __restrict__ Wt) {
    int id = blockIdx.x * 256 + threadIdx.x;   // 64 blocks
    int n = id >> 7, k = id & 127;
    Wt[n * 128 + k] = bf16_1(W[k * 128 + n]);
}

// ---------------------------------------------------------------------------
// K1: x = point_attr @ W via bf16 MFMA (16x16x32). 64 rows/block, 4 waves.
// ---------------------------------------------------------------------------
__global__ __launch_bounds__(256) void k_gemm_mfma(
    const float* __restrict__ A, const unsigned short* __restrict__ Wt,
    unsigned short* __restrict__ xb16, int N)
{
    __shared__ unsigned Al[64 * 64];   // [row][k2], 16 KB, slot-swizzled

    int t = threadIdx.x;
    int node0 = blockIdx.x * 64;

    const float4* A4 = (const float4*)A;
    #pragma unroll
    for (int it = 0; it < 8; ++it) {
        int id = it * 256 + t;
        int row = id >> 5, c = id & 31;
        float4 v = {0.f, 0.f, 0.f, 0.f};
        if (node0 + row < N) v = A4[(size_t)(node0 + row) * 32 + c];
        unsigned u0 = pack_bf16(v.x, v.y);
        unsigned u1 = pack_bf16(v.z, v.w);
        int k2 = 2 * c;
        int slot = k2 >> 2;
        int idx = ((slot ^ (row & 15)) << 2) | (k2 & 3);
        Al[row * 64 + idx]     = u0;
        Al[row * 64 + idx + 1] = u1;
    }
    __syncthreads();

    int l = t & 63;
    int w = t >> 6;
    int lrow = l & 15;
    int lk   = l >> 4;

    s8v afr[4];
    #pragma unroll
    for (int kb = 0; kb < 4; ++kb) {
        int slot = kb * 4 + lk;
        const unsigned* p = &Al[(w * 16 + lrow) * 64 + ((slot ^ lrow) << 2)];
        afr[kb] = *(const s8v*)p;
    }

    #pragma unroll
    for (int ct = 0; ct < 8; ++ct) {
        int col = ct * 16 + lrow;
        f4v acc = {0.f, 0.f, 0.f, 0.f};
        #pragma unroll
        for (int kb = 0; kb < 4; ++kb) {
            s8v bfr = *(const s8v*)&Wt[col * 128 + kb * 32 + lk * 8];
            acc = __builtin_amdgcn_mfma_f32_16x16x32_bf16(afr[kb], bfr, acc, 0, 0, 0);
        }
        #pragma unroll
        for (int r = 0; r < 4; ++r) {
            int node = node0 + w * 16 + lk * 4 + r;
            if (node < N) xb16[(size_t)node * 128 + col] = bf16_1(acc[r]);
        }
    }
}

// ---------------------------------------------------------------------------
// K1b: a_src/a_dst from bf16 x. 16 lanes/node.
// ---------------------------------------------------------------------------
__global__ __launch_bounds__(256) void k_att(
    const unsigned* __restrict__ xb, const float* __restrict__ att_src,
    const float* __restrict__ att_dst, float* __restrict__ a_src,
    float* __restrict__ a_dst, int N)
{
    int t = threadIdx.x;
    int node = blockIdx.x * 16 + (t >> 4);
    int lane = t & 15;
    if (node >= N) return;
    const uint4* x4 = (const uint4*)xb;
    uint4 xv = x4[(size_t)node * 16 + lane];
    int c = lane * 8;
    float xs[8];
    xs[0] = __uint_as_float(xv.x << 16); xs[1] = __uint_as_float(xv.x & 0xffff0000u);
    xs[2] = __uint_as_float(xv.y << 16); xs[3] = __uint_as_float(xv.y & 0xffff0000u);
    xs[4] = __uint_as_float(xv.z << 16); xs[5] = __uint_as_float(xv.z & 0xffff0000u);
    xs[6] = __uint_as_float(xv.w << 16); xs[7] = __uint_as_float(xv.w & 0xffff0000u);
    float ps = 0.f, pd = 0.f;
    #pragma unroll
    for (int i = 0; i < 8; ++i) {
        ps += xs[i] * att_src[c + i];
        pd += xs[i] * att_dst[c + i];
    }
    ps += __shfl_xor(ps, 1); ps += __shfl_xor(ps, 2);
    pd += __shfl_xor(pd, 1); pd += __shfl_xor(pd, 2);
    if ((lane & 3) == 0) {
        a_src[node * 4 + (lane >> 2)] = ps;
        a_dst[node * 4 + (lane >> 2)] = pd;
    }
}

// ---------------------------------------------------------------------------
// K2: degree histogram
// ---------------------------------------------------------------------------
__global__ __launch_bounds__(256) void k_degree(const int* __restrict__ ei,
                                                int* __restrict__ degree, int E) {
    int e = blockIdx.x * 256 + threadIdx.x;
    if (e < E) atomicAdd(&degree[ei[E + e]], 1);
}

// ---------------------------------------------------------------------------
// K3a/b/c: hierarchical exclusive scan
// ---------------------------------------------------------------------------
__global__ __launch_bounds__(1024) void k_scan_blk(
    const int* __restrict__ degree, int* __restrict__ local,
    int* __restrict__ blocksum, int N)
{
    __shared__ int sums[1024];
    int t = threadIdx.x;
    int base = blockIdx.x * 4096 + t * 4;
    int4 d = {0, 0, 0, 0};
    if (base + 3 < N) d = *(const int4*)&degree[base];
    else {
        if (base + 0 < N) d.x = degree[base + 0];
        if (base + 1 < N) d.y = degree[base + 1];
        if (base + 2 < N) d.z = degree[base + 2];
        if (base + 3 < N) d.w = degree[base + 3];
    }
    int s = d.x + d.y + d.z + d.w;
    sums[t] = s;
    __syncthreads();
    #pragma unroll
    for (int dd = 1; dd < 1024; dd <<= 1) {
        int v = (t >= dd) ? sums[t - dd] : 0;
        __syncthreads();
        sums[t] += v;
        __syncthreads();
    }
    int ex = sums[t] - s;
    if (t == 1023) blocksum[blockIdx.x] = sums[1023];
    int4 o;
    o.x = ex;
    o.y = o.x + d.x;
    o.z = o.y + d.y;
    o.w = o.z + d.z;
    if (base + 3 < N) *(int4*)&local[base] = o;
    else {
        if (base + 0 < N) local[base + 0] = o.x;
        if (base + 1 < N) local[base + 1] = o.y;
        if (base + 2 < N) local[base + 2] = o.z;
        if (base + 3 < N) local[base + 3] = o.w;
    }
}

__global__ __launch_bounds__(1024) void k_scan_top(
    int* __restrict__ blocksum, int nb, int* __restrict__ offsets, int N)
{
    __shared__ int sums[1024];
    int t = threadIdx.x;
    int v = (t < nb) ? blocksum[t] : 0;
    sums[t] = v;
    __syncthreads();
    #pragma unroll
    for (int d = 1; d < 1024; d <<= 1) {
        int u = (t >= d) ? sums[t - d] : 0;
        __syncthreads();
        sums[t] += u;
        __syncthreads();
    }
    if (t < nb) blocksum[t] = sums[t] - v;
    if (t == nb - 1) offsets[N] = sums[t];
}

__global__ __launch_bounds__(1024) void k_scan_add(
    const int* __restrict__ local, const int* __restrict__ blocksum,
    int* __restrict__ offsets, int* __restrict__ cursor, int N)
{
    int base = blockIdx.x * 4096 + threadIdx.x * 4;
    int bs = blocksum[blockIdx.x];
    if (base + 3 < N) {
        int4 o = *(const int4*)&local[base];
        o.x += bs; o.y += bs; o.z += bs; o.w += bs;
        *(int4*)&offsets[base] = o;
        *(int4*)&cursor[base]  = o;
    } else {
        for (int j = 0; j < 4; ++j)
            if (base + j < N) {
                int o = local[base + j] + bs;
                offsets[base + j] = o;
                cursor[base + j]  = o;
            }
    }
}

// ---------------------------------------------------------------------------
// K4: fused edge stream (R5/R10 winner): a_edge dot + exact-slot CSR scatter,
// ONE int4 (16B) per edge, plain store.
// ---------------------------------------------------------------------------
__global__ __launch_bounds__(256) void k_scatter(
    const float* __restrict__ edge_attr, const int* __restrict__ ei,
    const float* __restrict__ v_edge, int* __restrict__ cursor,
    int4* __restrict__ csr, int E)
{
    __shared__ float vl[HC];
    int t = threadIdx.x;
    if (t < HC) vl[t] = v_edge[t];
    __syncthreads();

    int e = blockIdx.x * 256 + t;
    if (e >= E) return;

    const float4* ea4 = (const float4*)edge_attr + (size_t)e * 8;
    float ae[4] = {0.f, 0.f, 0.f, 0.f};
    #pragma unroll
    for (int j = 0; j < 8; ++j) {
        float4 v = ea4[j];
        #pragma unroll
        for (int h = 0; h < 4; ++h) {
            const float* vh = &vl[h * 32 + j * 4];
            ae[h] += v.x * vh[0] + v.y * vh[1] + v.z * vh[2] + v.w * vh[3];
        }
    }
    int src = ei[e], dst = ei[E + e];
    int pos = atomicAdd(&cursor[dst], 1);
    int4 pk;
    pk.x = src;
    pk.y = (int)pack_bf16(ae[0], ae[1]);
    pk.z = (int)pack_bf16(ae[2], ae[3]);
    pk.w = 0;
    csr[pos] = pk;
}

// ---------------------------------------------------------------------------
// K5: fused pull, 16 lanes/node. logit finish + softmax + weighted sum +
// bias + LN + LeakyReLU. 4-edge groups with 1-ahead prefetch.
// x is L3-hot here: gemm/att run right before (CSR build reordered earlier).
// ---------------------------------------------------------------------------
__global__ __launch_bounds__(256) void k_agg(
    const int* __restrict__ offsets, const int4* __restrict__ csr,
    const float* __restrict__ a_src, const float* __restrict__ a_dst,
    const unsigned* __restrict__ xb, const float* __restrict__ bias,
    const float* __restrict__ gamma, const float* __restrict__ beta,
    float* __restrict__ out, int N)
{
    int t = threadIdx.x;
    int node = blockIdx.x * 16 + (t >> 4);
    int lane = t & 15;
    if (node >= N) return;
    int st = offsets[node], en = offsets[node + 1];
    int hsel = lane >> 2;
    float adst = a_dst[node * 4 + hsel];
    const uint4* x4 = (const uint4*)xb;
    float acc[8] = {0.f, 0.f, 0.f, 0.f, 0.f, 0.f, 0.f, 0.f};
    float denom = 0.f;

    int s_c[4]; float ae_c[4], as_c[4];

    if (st < en) {
        #pragma unroll
        for (int j = 0; j < 4; ++j) {
            bool v = (st + j) < en;
            int a = v ? (st + j) : st;
            int4 pk = csr[a];
            s_c[j] = pk.x;
            unsigned w = (hsel & 2) ? (unsigned)pk.z : (unsigned)pk.y;
            float e = __uint_as_float((hsel & 1) ? (w & 0xffff0000u) : (w << 16));
            ae_c[j] = v ? e : -1e30f;
        }
        #pragma unroll
        for (int j = 0; j < 4; ++j) as_c[j] = a_src[s_c[j] * 4 + hsel];

        for (int p = st; p < en; p += 4) {
            int pn = p + 4;
            int s_n[4]; float ae_n[4], as_n[4];
            #pragma unroll
            for (int j = 0; j < 4; ++j) {
                bool v = (pn + j) < en;
                int a = v ? (pn + j) : st;
                int4 pk = csr[a];
                s_n[j] = pk.x;
                unsigned w = (hsel & 2) ? (unsigned)pk.z : (unsigned)pk.y;
                float e = __uint_as_float((hsel & 1) ? (w & 0xffff0000u) : (w << 16));
                ae_n[j] = v ? e : -1e30f;
            }
            #pragma unroll
            for (int j = 0; j < 4; ++j) as_n[j] = a_src[s_n[j] * 4 + hsel];

            #pragma unroll
            for (int j = 0; j < 4; ++j) {
                float al = as_c[j] + adst + ae_c[j];
                al = (al < 0.f) ? 0.2f * al : al;
                float ex = __expf(al);
                denom += ex;
                uint4 xv = x4[(size_t)s_c[j] * 16 + lane];
                acc[0] += ex * __uint_as_float(xv.x << 16);
                acc[1] += ex * __uint_as_float(xv.x & 0xffff0000u);
                acc[2] += ex * __uint_as_float(xv.y << 16);
                acc[3] += ex * __uint_as_float(xv.y & 0xffff0000u);
                acc[4] += ex * __uint_as_float(xv.z << 16);
                acc[5] += ex * __uint_as_float(xv.z & 0xffff0000u);
                acc[6] += ex * __uint_as_float(xv.w << 16);
                acc[7] += ex * __uint_as_float(xv.w & 0xffff0000u);
            }
            #pragma unroll
            for (int j = 0; j < 4; ++j) {
                s_c[j] = s_n[j]; ae_c[j] = ae_n[j]; as_c[j] = as_n[j];
            }
        }
    }
    float inv = 1.f / (denom + 1e-16f);
    int c = lane * 8;
    float4 b0 = *(const float4*)&bias[c];
    float4 b1 = *(const float4*)&bias[c + 4];
    float o[8];
    o[0] = acc[0] * inv + b0.x; o[1] = acc[1] * inv + b0.y;
    o[2] = acc[2] * inv + b0.z; o[3] = acc[3] * inv + b0.w;
    o[4] = acc[4] * inv + b1.x; o[5] = acc[5] * inv + b1.y;
    o[6] = acc[6] * inv + b1.z; o[7] = acc[7] * inv + b1.w;

    float s = 0.f;
    #pragma unroll
    for (int i = 0; i < 8; ++i) s += o[i];
    #pragma unroll
    for (int m = 1; m < 16; m <<= 1) s += __shfl_xor(s, m, 16);
    float mu = s * (1.0f / 128.0f);
    float q = 0.f;
    #pragma unroll
    for (int i = 0; i < 8; ++i) { o[i] -= mu; q += o[i] * o[i]; }
    #pragma unroll
    for (int m = 1; m < 16; m <<= 1) q += __shfl_xor(q, m, 16);
    float rstd = rsqrtf(q * (1.0f / 128.0f) + 1e-5f);
    float4 g0 = *(const float4*)&gamma[c];
    float4 g1 = *(const float4*)&gamma[c + 4];
    float4 e0 = *(const float4*)&beta[c];
    float4 e1 = *(const float4*)&beta[c + 4];
    float y[8];
    y[0] = o[0] * rstd * g0.x + e0.x; y[1] = o[1] * rstd * g0.y + e0.y;
    y[2] = o[2] * rstd * g0.z + e0.z; y[3] = o[3] * rstd * g0.w + e0.w;
    y[4] = o[4] * rstd * g1.x + e1.x; y[5] = o[5] * rstd * g1.y + e1.y;
    y[6] = o[6] * rstd * g1.z + e1.z; y[7] = o[7] * rstd * g1.w + e1.w;
    #pragma unroll
    for (int i = 0; i < 8; ++i) y[i] = (y[i] < 0.f) ? 0.01f * y[i] : y[i];
    float4 r0 = {y[0], y[1], y[2], y[3]};
    float4 r1 = {y[4], y[5], y[6], y[7]};
    float4* op = (float4*)out + (size_t)node * 32 + lane * 2;
    op[0] = r0;
    op[1] = r1;
}

// ---------------------------------------------------------------------------
extern "C" void kernel_launch(void* const* d_in, const int* in_sizes, int n_in,
                              void* d_out, int out_size, void* d_ws, size_t ws_size,
                              hipStream_t stream) {
    const float* point_attr = (const float*)d_in[0];
    const int*   edge_index = (const int*)d_in[1];
    const float* edge_attr  = (const float*)d_in[2];
    const float* W          = (const float*)d_in[3];
    const float* att_src    = (const float*)d_in[4];
    const float* att_dst    = (const float*)d_in[5];
    const float* W_edge     = (const float*)d_in[6];
    const float* att_edge   = (const float*)d_in[7];
    const float* bias       = (const float*)d_in[8];
    const float* ln_gamma   = (const float*)d_in[9];
    const float* ln_beta    = (const float*)d_in[10];

    int N = in_sizes[0] / IN_DIM;
    int E = in_sizes[2] / EDGE_DIM;
    float* out = (float*)d_out;

    char* ws = (char*)d_ws;
    size_t off = 0;
    auto alloc = [&](size_t bytes) {
        void* p = ws + off;
        off += (bytes + 255) & ~(size_t)255;
        return p;
    };
    unsigned* xb     = (unsigned*)alloc((size_t)N * 128 * 2);   // bf16 x
    float* a_src     = (float*)alloc((size_t)N * 4 * 4);
    float* a_dst     = (float*)alloc((size_t)N * 4 * 4);
    int*   degree    = (int*)alloc((size_t)N * 4);
    int*   offsets   = (int*)alloc((size_t)(N + 1) * 4);
    int*   cursor    = (int*)alloc((size_t)N * 4);
    int*   scanloc   = (int*)alloc((size_t)N * 4);
    int*   blocksum  = (int*)alloc(1024 * 4);
    float* v_edge    = (float*)alloc(128 * 4);
    unsigned short* Wt = (unsigned short*)alloc(128 * 128 * 2);
    int4*  csr       = (int4*)alloc((size_t)E * 16);

    hipMemsetAsync(degree, 0, (size_t)N * 4, stream);

    int nb = (N + 4095) / 4096;

    // ---- CSR build FIRST (its 205MB stream pollutes L3 before x exists) ----
    k_vedge<<<1, 128, 0, stream>>>(W_edge, att_edge, v_edge);
    k_degree<<<(E + 255) / 256, 256, 0, stream>>>(edge_index, degree, E);
    k_scan_blk<<<nb, 1024, 0, stream>>>(degree, scanloc, blocksum, N);
    k_scan_top<<<1, 1024, 0, stream>>>(blocksum, nb, offsets, N);
    k_scan_add<<<nb, 1024, 0, stream>>>(scanloc, blocksum, offsets, cursor, N);
    k_scatter<<<(E + 255) / 256, 256, 0, stream>>>(edge_attr, edge_index, v_edge,
                                                   cursor, csr, E);
    // ---- then x (stays L3-hot into k_agg) ----
    k_prep<<<64, 256, 0, stream>>>(W, Wt);
    k_gemm_mfma<<<(N + 63) / 64, 256, 0, stream>>>(point_attr, Wt,
                                                   (unsigned short*)xb, N);
    k_att<<<(N + 15) / 16, 256, 0, stream>>>(xb, att_src, att_dst,
                                             a_src, a_dst, N);
    // ---- aggregate ----
    k_agg<<<(N + 15) / 16, 256, 0, stream>>>(offsets, csr, a_src, a_dst, xb,
                                             bias, ln_gamma, ln_beta, out, N);
}